// Round 10
// baseline (212.137 us; speedup 1.0000x reference)
//
#include <hip/hip_runtime.h>
#include <hip/hip_bf16.h>
#include <cstdint>
#include <cstddef>

// ---- problem constants ----
#define BATCH 2
#define SEQ   2048
#define DM    1024
#define NH    16
#define DK    64
#define MROWS (BATCH*SEQ)   // 4096

typedef __bf16 bf16;
typedef float  f32x4  __attribute__((ext_vector_type(4)));
typedef bf16   bf16x8 __attribute__((ext_vector_type(8)));
typedef bf16   bf16x4 __attribute__((ext_vector_type(4)));

// verified (m89/m120): A[m=lane&15][k=(lane>>4)*8+j], B[n=lane&15][k=(lane>>4)*8+j],
// C/D: col(n)=lane&15, row(m)=(lane>>4)*4+reg
#define MFMA32(a, b, c) __builtin_amdgcn_mfma_f32_16x16x32_bf16(a, b, c, 0, 0, 0)

// async global->LDS, 16B per lane; LDS dest is wave-uniform base + lane*16
__device__ __forceinline__ void llds16(const void* gc, void* l) {
    void* g = (void*)gc;
    __builtin_amdgcn_global_load_lds(
        (__attribute__((address_space(1))) uint32_t*)g,
        (__attribute__((address_space(3))) uint32_t*)l,
        16, 0, 0);
}

// ---------------- fused fp32 -> bf16 convert (q,k,v + 4 weights) ----------------
__global__ __launch_bounds__(256) void k_convert(
    const float* __restrict__ q, const float* __restrict__ k, const float* __restrict__ v,
    const float* __restrict__ wq, const float* __restrict__ wk, const float* __restrict__ wv,
    const float* __restrict__ wo,
    bf16* __restrict__ qb, bf16* __restrict__ kb, bf16* __restrict__ vb,
    bf16* __restrict__ wqb, bf16* __restrict__ wkb, bf16* __restrict__ wvb,
    bf16* __restrict__ wob) {
    long t = (long)blockIdx.x * blockDim.x + threadIdx.x;   // one float4 per thread
    const long NQ = (long)MROWS * DM / 4;
    const long NW = (long)DM * DM / 4;
    const float* src; bf16* dst; long off;
    if (t < NQ)            { src = q;  dst = qb;  off = t; }
    else if (t < 2*NQ)     { src = k;  dst = kb;  off = t - NQ; }
    else if (t < 3*NQ)     { src = v;  dst = vb;  off = t - 2*NQ; }
    else {
        long u = t - 3*NQ;
        if (u < NW)        { src = wq; dst = wqb; off = u; }
        else if (u < 2*NW) { src = wk; dst = wkb; off = u - NW; }
        else if (u < 3*NW) { src = wv; dst = wvb; off = u - 2*NW; }
        else               { src = wo; dst = wob; off = u - 3*NW; }
    }
    f32x4 x = *(const f32x4*)(src + off * 4);
    bf16x4 y;
    y[0] = (bf16)x[0]; y[1] = (bf16)x[1]; y[2] = (bf16)x[2]; y[3] = (bf16)x[3];
    *(bf16x4*)(dst + off * 4) = y;
}

// ---- merged Q/K/V projections: 128(M)x128(N) tiles, 4 waves, 4x4 acc, BK=64 swz ----
// (r9 version, unchanged this round; qkv ~41us across 3 configs = 2-phase floor.)
// Qf/Kf entry (bh, s16 = s>>4, chunk = d>>5): lane l, elem e holds
//   [s-in-16 = l&15][d-in-32 = (l>>4)*8 + e]   (= MFMA A/B-operand order)
// Vf entry (bh, kc = s>>5, dtile = d>>4): PERMUTED k-slot order pi(quad*8+e) =
//   (e>>2)*16 + quad*4 + (e&3), so the flash P B-fragment needs NO lane exchange.
__global__ __launch_bounds__(256, 4) void k_gemm_qkv(
    const bf16* __restrict__ qb, const bf16* __restrict__ kb, const bf16* __restrict__ vb,
    const bf16* __restrict__ wqb, const bf16* __restrict__ wkb, const bf16* __restrict__ wvb,
    const float* __restrict__ bq, const float* __restrict__ bk, const float* __restrict__ bv,
    bf16* __restrict__ Qf, bf16* __restrict__ Kf, bf16* __restrict__ Vf) {
    const int z = blockIdx.z;
    const int bid = blockIdx.x;
    const bf16* A; const bf16* B; const float* bias;
    int m0, n0;
    if (z == 2) {
        A = vb; B = wvb; bias = bv;
        m0 = (bid >> 3) * 128;        // s block (32 of them)
        n0 = (bid & 7) * 128;         // feature block (8)
    } else {
        A = z ? wkb : wqb; B = z ? kb : qb; bias = z ? bk : bq;
        m0 = (bid >> 5) * 128;        // feature block (8)
        n0 = (bid & 31) * 128;        // s block (32)
    }

    constexpr int K = DM, BK = 64;    // 16 K-steps
    __shared__ bf16 sA[128 * BK];     // 16 KB, row stride 128B
    __shared__ bf16 sB[128 * BK];     // 16 KB
    const int tid = threadIdx.x;
    const int l = tid & 63, w = tid >> 6;        // w = 0..3
    const int quad = l >> 4, l15 = l & 15;
    const int wm = w & 1, wn = w >> 1;           // 2(M) x 2(N), 64x64 per wave
    const int srow = l >> 3;                     // row within 8-row staging group
    const int scol = ((l & 7) ^ srow) * 8;       // inverse-swizzled source slot

    f32x4 acc[4][4] = {};
    for (int k0 = 0; k0 < K; k0 += BK) {
#pragma unroll
        for (int i = 0; i < 4; ++i) {            // A+B: wave stages groups w*4..w*4+3
            int r8 = (w * 4 + i) * 8;
            llds16(A + (size_t)(m0 + r8 + srow) * K + k0 + scol, &sA[r8 * BK]);
            llds16(B + (size_t)(n0 + r8 + srow) * K + k0 + scol, &sB[r8 * BK]);
        }
        __syncthreads();

#pragma unroll
        for (int kk = 0; kk < 2; ++kk) {
            bf16x8 af[4], bfr[4];
#pragma unroll
            for (int mi = 0; mi < 4; ++mi) {
                int row = wm * 64 + mi * 16 + l15;
                int byt = (row * 128 + kk * 64 + quad * 16) ^ ((row & 7) << 4);
                af[mi] = *(const bf16x8*)((const char*)sA + byt);
            }
#pragma unroll
            for (int ni = 0; ni < 4; ++ni) {
                int row = wn * 64 + ni * 16 + l15;
                int byt = (row * 128 + kk * 64 + quad * 16) ^ ((row & 7) << 4);
                bfr[ni] = *(const bf16x8*)((const char*)sB + byt);
            }
#pragma unroll
            for (int mi = 0; mi < 4; ++mi)
#pragma unroll
                for (int ni = 0; ni < 4; ++ni)
                    acc[mi][ni] = MFMA32(af[mi], bfr[ni], acc[mi][ni]);
        }
        __syncthreads();
    }

    if (z == 2) {
        // V epilogue (verified r1-r3): acc elem = V[s = m0+wm*64+mi*16+quad*4+r]
        //                                         [d = n0+wn*64+ni*16+l15]
#pragma unroll
        for (int ni = 0; ni < 4; ++ni) {
            int dcol = n0 + wn * 64 + ni * 16 + l15;
            int hh2 = dcol >> 6;                 // head
            int dtile = (dcol >> 4) & 3;         // (d&63)>>4
            float bias_v = bias[dcol];
#pragma unroll
            for (int mi = 0; mi < 4; ++mi) {
                int srw = m0 + wm * 64 + mi * 16;
                int bb = srw >> 11, sl = srw & 2047;
                int kc = sl >> 5;
                bf16x4 pack;
#pragma unroll
                for (int r = 0; r < 4; ++r)
                    pack[r] = (bf16)(acc[mi][ni][r] + bias_v);
                size_t entry = ((size_t)(bb * NH + hh2) * 64 + kc) * 4 + dtile;
                *(bf16x4*)(Vf + entry * 512 + (size_t)(quad * 16 + l15) * 8 + (mi & 1) * 4) = pack;
            }
        }
    } else {
        // Q/K epilogue (verified r1-r3): acc elem = D[feat = m0+wm*64+mi*16+quad*4+r]
        //                                            [s = n0+wn*64+ni*16+l15]
        bf16* out = z ? Kf : Qf;
        const float scale = z ? 1.0f : 0.18033688f;   // Q carries 0.125 * log2(e)
        float bias_rv[4][4];
#pragma unroll
        for (int mi = 0; mi < 4; ++mi)
#pragma unroll
            for (int r = 0; r < 4; ++r)
                bias_rv[mi][r] = bias[m0 + wm * 64 + mi * 16 + quad * 4 + r];
#pragma unroll
        for (int ni = 0; ni < 4; ++ni) {
            int scolg = n0 + wn * 64 + ni * 16 + l15;
            int bb = scolg >> 11, s = scolg & 2047;
            int s16 = s >> 4;
#pragma unroll
            for (int mi = 0; mi < 4; ++mi) {
                int drow = m0 + wm * 64 + mi * 16;
                int hh2 = (drow >> 6) & 15;
                int chunk = (drow & 63) >> 5;
                int qp = 2 * (mi & 1) + (quad >> 1);   // (d32)>>3
                bf16x4 pack;
#pragma unroll
                for (int r = 0; r < 4; ++r)
                    pack[r] = (bf16)((acc[mi][ni][r] + bias_rv[mi][r]) * scale);
                size_t entry = ((size_t)(bb * NH + hh2) * 128 + s16) * 2 + chunk;
                *(bf16x4*)(out + entry * 512 + (size_t)(qp * 16 + l15) * 8 + (quad & 1) * 4) = pack;
            }
        }
    }
}

// ---- output projection: 128(M)x64(N), BK=64 swizzled, dbuf, 8 WAVES (r7) ----
__global__ __launch_bounds__(512, 4) void k_gemm_out(
    const bf16* __restrict__ X, const bf16* __restrict__ wob,
    const float* __restrict__ bo, float* __restrict__ out) {
    constexpr int K = DM, BK = 64, NS = K / BK;   // 16 steps
    const int m0 = blockIdx.y * 128, n0 = blockIdx.x * 64;
    __shared__ bf16 sA[2][128 * BK];   // 32 KB
    __shared__ bf16 sB[2][64 * BK];    // 16 KB
    const int tid = threadIdx.x;
    const int l = tid & 63, w = tid >> 6;
    const int quad = l >> 4, l15 = l & 15;
    const int wm = w & 1, wn = w >> 1;
    const int srow = l >> 3;
    const int scol = ((l & 7) ^ srow) * 8;

#pragma unroll
    for (int i = 0; i < 2; ++i) {
        int g8 = (w * 2 + i) * 8;
        llds16(X + (size_t)(m0 + g8 + srow) * K + scol, &sA[0][g8 * BK]);
    }
    llds16(wob + (size_t)(n0 + w * 8 + srow) * K + scol, &sB[0][(w * 8) * BK]);

    f32x4 acc[4] = {};
    for (int s = 0; s < NS; ++s) {
        __syncthreads();
        const int cur = s & 1;
        if (s + 1 < NS) {
            const int k0 = (s + 1) * BK;
#pragma unroll
            for (int i = 0; i < 2; ++i) {
                int g8 = (w * 2 + i) * 8;
                llds16(X + (size_t)(m0 + g8 + srow) * K + k0 + scol, &sA[cur ^ 1][g8 * BK]);
            }
            llds16(wob + (size_t)(n0 + w * 8 + srow) * K + k0 + scol, &sB[cur ^ 1][(w * 8) * BK]);
        }

#pragma unroll
        for (int kk = 0; kk < 2; ++kk) {
            bf16x8 af[4], bfr;
            {
                int row = wn * 16 + l15;
                int byt = (row * 128 + kk * 64 + quad * 16) ^ ((row & 7) << 4);
                bfr = *(const bf16x8*)((const char*)&sB[cur][0] + byt);
            }
#pragma unroll
            for (int mi = 0; mi < 4; ++mi) {
                int row = wm * 64 + mi * 16 + l15;
                int byt = (row * 128 + kk * 64 + quad * 16) ^ ((row & 7) << 4);
                af[mi] = *(const bf16x8*)((const char*)&sA[cur][0] + byt);
            }
#pragma unroll
            for (int mi = 0; mi < 4; ++mi)
                acc[mi] = MFMA32(af[mi], bfr, acc[mi]);
        }
    }
    {
        int col = n0 + wn * 16 + l15;
        float bias_v = bo[col];
#pragma unroll
        for (int mi = 0; mi < 4; ++mi) {
            int rbase = m0 + wm * 64 + mi * 16 + quad * 4;
#pragma unroll
            for (int r = 0; r < 4; ++r)
                out[(size_t)(rbase + r) * DM + col] = acc[mi][r] + bias_v;
        }
    }
}

// ---------------- causal flash attention: 2x2 wave split (halved LDS reads) ----------------
// Round-10: flash is LDS-read-pipe bound (~21us of ~28us: 4 waves x 16KB identical
// reads per block-iter = 4.2MB/CU at 85 B/cy). Split: wave (wq = w>>1, wk = w&1)
// owns 32 queries (wq) x 32 keys (wk) -> per-iter reads only its K half (4 entries)
// + V half (4 entries) = 8KB. PV runs full k=32 depth (wk's keys exactly fill one
// Vf kc-chunk: pb[e] = E[e>>2][qs][e&3], same verified pi algebra, zero waste).
// MFMA count unchanged (8 QK + 8 PV / wave-iter). One-time cross-wave combine:
// wk=1 publishes partial O (8KB) + lp to LDS; wk=0 sums, normalizes, stores.
// Staging / grid (bh=32, 32 LPT) / dbuf structure unchanged.
__global__ __launch_bounds__(256, 4) void k_flash(const bf16* __restrict__ Qf,
                                                  const bf16* __restrict__ Kf,
                                                  const bf16* __restrict__ Vf,
                                                  bf16* __restrict__ X) {
    const int bh = blockIdx.x;
    const int qt = 31 - (int)blockIdx.y;      // LPT order
    const int b = bh >> 4, h = bh & 15;
    const int tid = threadIdx.x, w = tid >> 6, l = tid & 63;
    const int quad = l >> 4, l15 = l & 15;
    const int wq = w >> 1, wk = w & 1;
    __shared__ bf16 sKV[2][16 * 512];         // [buf][e]: e 0..7 = K (ni*2+c), 8..15 = V (8+c32*4+dt)

    const bf16* qfp = Qf + (size_t)bh * 128 * 1024;
    const bf16* kfp = Kf + (size_t)bh * 128 * 1024;
    const bf16* vfp = Vf + (size_t)bh * 64 * 4 * 512;

    // persistent Q B-frags: queries qt*64 + wq*32 + qs*16 + l15; [qs][chunk]
    bf16x8 qf[2][2];
#pragma unroll
    for (int qs = 0; qs < 2; ++qs)
#pragma unroll
        for (int c = 0; c < 2; ++c)
            qf[qs][c] = *(const bf16x8*)(qfp
                + ((size_t)(qt * 4 + wq * 2 + qs) * 2 + c) * 512 + (size_t)l * 8);

    f32x4 o[2][4] = {};         // [qs][dt]: O^T row = d-in-16, col = query = l15
    float lp[2] = {0.f, 0.f};   // per-lane partial denom per query-subtile

    // preload tile 0: wave w stages entries w*4..w*4+3 (full 16-entry tile)
#pragma unroll
    for (int i = 0; i < 4; ++i) {
        int e = w * 4 + i;
        const bf16* src = (e < 8) ? kfp + ((size_t)e) * 512
                                  : vfp + ((size_t)(e - 8)) * 512;
        llds16(src + (size_t)l * 8, &sKV[0][e * 512]);
    }

    for (int j = 0; j <= qt; ++j) {
        __syncthreads();        // staging of tile j (issued last iter) now visible
        const bf16* cur = sKV[j & 1];
        if (j < qt) {
            int j1 = j + 1;
#pragma unroll
            for (int i = 0; i < 4; ++i) {
                int e = w * 4 + i;
                const bf16* src = (e < 8) ? kfp + ((size_t)(j1 * 8 + e)) * 512
                                          : vfp + ((size_t)(j1 * 8 + (e - 8))) * 512;
                llds16(src + (size_t)l * 8, (void*)&sKV[j1 & 1][e * 512]);
            }
        }

        // ---- S^T = K.Q^T: this wave's 32 keys (wk half) x its 32 queries (wq half) ----
        f32x4 st[2][2];         // [ni2 = key-16-subtile][qs]
#pragma unroll
        for (int ni2 = 0; ni2 < 2; ++ni2) {
            int e0 = (wk * 2 + ni2) * 2;
            bf16x8 k0 = *(const bf16x8*)&cur[(size_t)(e0 + 0) * 512 + l * 8];
            bf16x8 k1 = *(const bf16x8*)&cur[(size_t)(e0 + 1) * 512 + l * 8];
#pragma unroll
            for (int qs = 0; qs < 2; ++qs) {
                f32x4 zz = {};
                zz = MFMA32(k0, qf[qs][0], zz);
                st[ni2][qs] = MFMA32(k1, qf[qs][1], zz);
            }
        }

        // ---- V half (4 entries, hoisted; shared across qs) ----
        bf16x8 vv[4];
#pragma unroll
        for (int dt = 0; dt < 4; ++dt)
            vv[dt] = *(const bf16x8*)&cur[(size_t)(8 + wk * 4 + dt) * 512 + l * 8];

        // ---- fixed-m softmax (log2 domain) + in-register P + PV ----
        const bool diag = (j == qt);
#pragma unroll
        for (int qs = 0; qs < 2; ++qs) {
            bf16x8 pb;
#pragma unroll
            for (int ni2 = 0; ni2 < 2; ++ni2) {
#pragma unroll
                for (int r = 0; r < 4; ++r) {
                    float s = st[ni2][qs][r];
                    if (diag) {
                        int key = wk * 32 + ni2 * 16 + quad * 4 + r;  // tile-local
                        int qq  = wq * 32 + qs * 16 + l15;            // tile-local
                        if (key > qq) s = -1e30f;
                    }
                    float e = __builtin_amdgcn_exp2f(s);
                    lp[qs] += e;
                    pb[ni2 * 4 + r] = (bf16)e;   // slot e: ni2 = e>>2, r = e&3
                }
            }
#pragma unroll
            for (int dt = 0; dt < 4; ++dt)
                o[qs][dt] = MFMA32(vv[dt], pb, o[qs][dt]);
        }
    }

    // ---- quad-reduce lp (sum over this wave's 32 keys; queries are per-lane) ----
#pragma unroll
    for (int qs = 0; qs < 2; ++qs) {
        lp[qs] += __shfl_xor(lp[qs], 16, 64);
        lp[qs] += __shfl_xor(lp[qs], 32, 64);
    }

    // ---- cross-wave combine: wk=1 publishes partials, wk=0 sums + stores ----
    __syncthreads();            // all waves done reading sKV
    float* lpbuf = (float*)&sKV[0][0];     // [wq][qs][l15] : 64 f32 = 256B
    float* obuf  = (float*)&sKV[1][0];     // [wq][qs][dt][row16][l15] : 4096 f32 = 16KB
    if (wk == 1) {
        if (quad == 0) {
            lpbuf[(wq * 2 + 0) * 16 + l15] = lp[0];
            lpbuf[(wq * 2 + 1) * 16 + l15] = lp[1];
        }
#pragma unroll
        for (int qs = 0; qs < 2; ++qs)
#pragma unroll
            for (int dt = 0; dt < 4; ++dt)
#pragma unroll
                for (int r = 0; r < 4; ++r)
                    obuf[(((wq * 2 + qs) * 4 + dt) * 16 + quad * 4 + r) * 16 + l15] = o[qs][dt][r];
    }
    __syncthreads();
    if (wk == 0) {
#pragma unroll
        for (int qs = 0; qs < 2; ++qs) {
            float lt = lp[qs] + lpbuf[(wq * 2 + qs) * 16 + l15];
            float rv = 1.f / lt;
#pragma unroll
            for (int dt = 0; dt < 4; ++dt)
#pragma unroll
                for (int r = 0; r < 4; ++r)
                    o[qs][dt][r] = (o[qs][dt][r]
                        + obuf[(((wq * 2 + qs) * 4 + dt) * 16 + quad * 4 + r) * 16 + l15]) * rv;
        }
        // ---- repack via LDS (regions after lpbuf), coalesced store: 2 subtiles ----
#pragma unroll
        for (int qs = 0; qs < 2; ++qs) {
            bf16* Xw = &sKV[0][128 + (wq * 2 + qs) * 1152];   // 16 x 72 bf16 region
#pragma unroll
            for (int dt = 0; dt < 4; ++dt) {
                bf16x4 pk;
#pragma unroll
                for (int r = 0; r < 4; ++r)
                    pk[r] = (bf16)o[qs][dt][r];
                *(bf16x4*)&Xw[l15 * 72 + dt * 16 + quad * 4] = pk;
            }
            int s16g = qt * 4 + wq * 2 + qs;
#pragma unroll
            for (int i = 0; i < 2; ++i) {
                int row = i * 8 + (l >> 3);
                bf16x8 v8 = *(const bf16x8*)&Xw[row * 72 + (l & 7) * 8];
                *(bf16x8*)(X + (size_t)(b * SEQ + s16g * 16 + row) * DM + h * 64 + (l & 7) * 8) = v8;
            }
        }
    }
}

// ---------------- launcher ----------------
extern "C" void kernel_launch(void* const* d_in, const int* in_sizes, int n_in,
                              void* d_out, int out_size, void* d_ws, size_t ws_size,
                              hipStream_t stream) {
    const float* q  = (const float*)d_in[0];
    const float* k  = (const float*)d_in[1];
    const float* v  = (const float*)d_in[2];
    // d_in[3] = mask: causal tril, handled analytically
    const float* wq = (const float*)d_in[4];
    const float* bq = (const float*)d_in[5];
    const float* wk = (const float*)d_in[6];
    const float* bk = (const float*)d_in[7];
    const float* wv = (const float*)d_in[8];
    const float* bv = (const float*)d_in[9];
    const float* wo = (const float*)d_in[10];
    const float* bo = (const float*)d_in[11];
    float* out = (float*)d_out;

    uint8_t* ws = (uint8_t*)d_ws;
    const size_t SZ_ACT = (size_t)MROWS * DM * sizeof(bf16);  // 8 MB
    const size_t SZ_W   = (size_t)DM * DM * sizeof(bf16);     // 2 MB
    bf16* qb  = (bf16*)(ws);
    bf16* kb  = (bf16*)(ws + SZ_ACT);
    bf16* vb  = (bf16*)(ws + 2 * SZ_ACT);
    bf16* wqb = (bf16*)(ws + 3 * SZ_ACT);
    bf16* wkb = (bf16*)(ws + 3 * SZ_ACT + SZ_W);
    bf16* wvb = (bf16*)(ws + 3 * SZ_ACT + 2 * SZ_W);
    bf16* wob = (bf16*)(ws + 3 * SZ_ACT + 3 * SZ_W);
    bf16* Qf  = (bf16*)(ws + 3 * SZ_ACT + 4 * SZ_W);
    bf16* Kf  = (bf16*)(ws + 4 * SZ_ACT + 4 * SZ_W);
    bf16* Vf  = (bf16*)(ws + 5 * SZ_ACT + 4 * SZ_W);
    bf16* X   = (bf16*)(ws + 6 * SZ_ACT + 4 * SZ_W);
    // total: 7*SZ_ACT + 4*SZ_W = 64 MB

    // 1) convert to bf16
    {
        long total_vec4 = 3L * MROWS * DM / 4 + 4L * DM * DM / 4;
        k_convert<<<dim3((unsigned)(total_vec4 / 256)), 256, 0, stream>>>(
            q, k, v, wq, wk, wv, wo, qb, kb, vb, wqb, wkb, wvb, wob);
    }
    // 2) merged Q/K/V projections: 128x128 tiles, 4 waves, BK=64 swizzled, 3 blk/CU
    k_gemm_qkv<<<dim3(256, 1, 3), 256, 0, stream>>>(
        qb, kb, vb, wqb, wkb, wvb, bq, bk, bv, Qf, Kf, Vf);
    // 3) causal flash attention (2x2 wave split: 32q x 32k per wave, LPT)
    k_flash<<<dim3(BATCH * NH, SEQ / 64), 256, 0, stream>>>(Qf, Kf, Vf, X);
    // 4) output projection -> fp32 (128x64 tiles, BK=64 swizzled, 8 waves, dbuf)
    k_gemm_out<<<dim3(DM / 64, MROWS / 128), 512, 0, stream>>>(X, wob, bo, out);
}

// Round 11
// 206.916 us; speedup vs baseline: 1.0252x; 1.0252x over previous
//
#include <hip/hip_runtime.h>
#include <hip/hip_bf16.h>
#include <cstdint>
#include <cstddef>

// ---- problem constants ----
#define BATCH 2
#define SEQ   2048
#define DM    1024
#define NH    16
#define DK    64
#define MROWS (BATCH*SEQ)   // 4096

typedef __bf16 bf16;
typedef float  f32x4  __attribute__((ext_vector_type(4)));
typedef bf16   bf16x8 __attribute__((ext_vector_type(8)));
typedef bf16   bf16x4 __attribute__((ext_vector_type(4)));

// verified (m89/m120): A[m=lane&15][k=(lane>>4)*8+j], B[n=lane&15][k=(lane>>4)*8+j],
// C/D: col(n)=lane&15, row(m)=(lane>>4)*4+reg
#define MFMA32(a, b, c) __builtin_amdgcn_mfma_f32_16x16x32_bf16(a, b, c, 0, 0, 0)

// async global->LDS, 16B per lane; LDS dest is wave-uniform base + lane*16
__device__ __forceinline__ void llds16(const void* gc, void* l) {
    void* g = (void*)gc;
    __builtin_amdgcn_global_load_lds(
        (__attribute__((address_space(1))) uint32_t*)g,
        (__attribute__((address_space(3))) uint32_t*)l,
        16, 0, 0);
}

// ---------------- fused fp32 -> bf16 convert (q,k,v + 4 weights) ----------------
__global__ __launch_bounds__(256) void k_convert(
    const float* __restrict__ q, const float* __restrict__ k, const float* __restrict__ v,
    const float* __restrict__ wq, const float* __restrict__ wk, const float* __restrict__ wv,
    const float* __restrict__ wo,
    bf16* __restrict__ qb, bf16* __restrict__ kb, bf16* __restrict__ vb,
    bf16* __restrict__ wqb, bf16* __restrict__ wkb, bf16* __restrict__ wvb,
    bf16* __restrict__ wob) {
    long t = (long)blockIdx.x * blockDim.x + threadIdx.x;   // one float4 per thread
    const long NQ = (long)MROWS * DM / 4;
    const long NW = (long)DM * DM / 4;
    const float* src; bf16* dst; long off;
    if (t < NQ)            { src = q;  dst = qb;  off = t; }
    else if (t < 2*NQ)     { src = k;  dst = kb;  off = t - NQ; }
    else if (t < 3*NQ)     { src = v;  dst = vb;  off = t - 2*NQ; }
    else {
        long u = t - 3*NQ;
        if (u < NW)        { src = wq; dst = wqb; off = u; }
        else if (u < 2*NW) { src = wk; dst = wkb; off = u - NW; }
        else if (u < 3*NW) { src = wv; dst = wvb; off = u - 2*NW; }
        else               { src = wo; dst = wob; off = u - 3*NW; }
    }
    f32x4 x = *(const f32x4*)(src + off * 4);
    bf16x4 y;
    y[0] = (bf16)x[0]; y[1] = (bf16)x[1]; y[2] = (bf16)x[2]; y[3] = (bf16)x[3];
    *(bf16x4*)(dst + off * 4) = y;
}

// ---- merged Q/K/V projections: 128(M)x64(N) tiles, BK=64 swizzled, 8 WAVES ----
// r7 config verbatim (measured best total 207.0us; qkv 40.8us, VGPR 32, occ 51%,
// conflicts 0). qkv has pinned ~41us across 3 structurally different configs
// (6-blk 128x64, 32-wave 8-wave, 3-blk 128x128 4x4) -> 2-phase structural floor.
// Qf/Kf entry (bh, s16 = s>>4, chunk = d>>5): lane l, elem e holds
//   [s-in-16 = l&15][d-in-32 = (l>>4)*8 + e]   (= MFMA A/B-operand order)
// Vf entry (bh, kc = s>>5, dtile = d>>4): PERMUTED k-slot order pi(quad*8+e) =
//   (e>>2)*16 + quad*4 + (e&3), so the flash P B-fragment needs NO lane exchange.
__global__ __launch_bounds__(512, 8) void k_gemm_qkv(
    const bf16* __restrict__ qb, const bf16* __restrict__ kb, const bf16* __restrict__ vb,
    const bf16* __restrict__ wqb, const bf16* __restrict__ wkb, const bf16* __restrict__ wvb,
    const float* __restrict__ bq, const float* __restrict__ bk, const float* __restrict__ bv,
    bf16* __restrict__ Qf, bf16* __restrict__ Kf, bf16* __restrict__ Vf) {
    const int z = blockIdx.z;
    const int bid = blockIdx.x;
    const bf16* A; const bf16* B; const float* bias;
    int m0, n0;
    if (z == 2) {
        A = vb; B = wvb; bias = bv;
        m0 = (bid >> 4) * 128;        // s block (32 of them)
        n0 = (bid & 15) * 64;         // feature block (16)
    } else {
        A = z ? wkb : wqb; B = z ? kb : qb; bias = z ? bk : bq;
        m0 = (bid >> 6) * 128;        // feature block (8)
        n0 = (bid & 63) * 64;         // s block (64)
    }

    constexpr int K = DM, BK = 64;    // 16 K-steps
    __shared__ bf16 sA[128 * BK];     // 16 KB, row stride 128B
    __shared__ bf16 sB[64 * BK];      // 8 KB
    const int tid = threadIdx.x;
    const int l = tid & 63, w = tid >> 6;        // w = 0..7
    const int quad = l >> 4, l15 = l & 15;
    const int wm = w & 1, wn = w >> 1;           // 2 M-halves x 4 N-strips of 16
    const int srow = l >> 3;                     // row within 8-row staging group
    const int scol = ((l & 7) ^ srow) * 8;       // inverse-swizzled source slot

    f32x4 acc[4] = {};
    for (int k0 = 0; k0 < K; k0 += BK) {
#pragma unroll
        for (int i = 0; i < 2; ++i) {            // A: wave stages groups w*2, w*2+1
            int g8 = (w * 2 + i) * 8;
            llds16(A + (size_t)(m0 + g8 + srow) * K + k0 + scol, &sA[g8 * BK]);
        }
        {                                        // B: wave stages group w (rows w*8..+7)
            int g8 = w * 8;
            llds16(B + (size_t)(n0 + g8 + srow) * K + k0 + scol, &sB[g8 * BK]);
        }
        __syncthreads();

#pragma unroll
        for (int kk = 0; kk < 2; ++kk) {
            bf16x8 af[4], bfr;
            {
                int row = wn * 16 + l15;
                int byt = (row * 128 + kk * 64 + quad * 16) ^ ((row & 7) << 4);
                bfr = *(const bf16x8*)((const char*)sB + byt);
            }
#pragma unroll
            for (int mi = 0; mi < 4; ++mi) {
                int row = wm * 64 + mi * 16 + l15;
                int byt = (row * 128 + kk * 64 + quad * 16) ^ ((row & 7) << 4);
                af[mi] = *(const bf16x8*)((const char*)sA + byt);
            }
#pragma unroll
            for (int mi = 0; mi < 4; ++mi)
                acc[mi] = MFMA32(af[mi], bfr, acc[mi]);
        }
        __syncthreads();
    }

    if (z == 2) {
        // V epilogue: acc element = V[s = m0+wm*64+mi*16+quad*4+r][d = n0+wn*16+l15]
        int dcol = n0 + wn * 16 + l15;
        int hh2 = dcol >> 6;                 // head
        int dtile = (dcol >> 4) & 3;         // (d&63)>>4
        float bias_v = bias[dcol];
#pragma unroll
        for (int mi = 0; mi < 4; ++mi) {
            int srw = m0 + wm * 64 + mi * 16;
            int bb = srw >> 11, sl = srw & 2047;
            int kc = sl >> 5;
            bf16x4 pack;
#pragma unroll
            for (int r = 0; r < 4; ++r)
                pack[r] = (bf16)(acc[mi][r] + bias_v);
            size_t entry = ((size_t)(bb * NH + hh2) * 64 + kc) * 4 + dtile;
            *(bf16x4*)(Vf + entry * 512 + (size_t)(quad * 16 + l15) * 8 + (mi & 1) * 4) = pack;
        }
    } else {
        // Q/K epilogue: acc element = D[feature = m0+wm*64+mi*16+quad*4+r][s = n0+wn*16+l15]
        bf16* out = z ? Kf : Qf;
        const float scale = z ? 1.0f : 0.18033688f;   // Q carries 0.125 * log2(e)
        int scolg = n0 + wn * 16 + l15;
        int bb = scolg >> 11, s = scolg & 2047;
        int s16 = s >> 4;
#pragma unroll
        for (int mi = 0; mi < 4; ++mi) {
            int drow = m0 + wm * 64 + mi * 16;
            int hh2 = (drow >> 6) & 15;
            int chunk = (drow & 63) >> 5;
            int qp = 2 * (mi & 1) + (quad >> 1);   // (d32)>>3
            bf16x4 pack;
#pragma unroll
            for (int r = 0; r < 4; ++r)
                pack[r] = (bf16)((acc[mi][r] + bias[drow + quad * 4 + r]) * scale);
            size_t entry = ((size_t)(bb * NH + hh2) * 128 + s16) * 2 + chunk;
            *(bf16x4*)(out + entry * 512 + (size_t)(qp * 16 + l15) * 8 + (quad & 1) * 4) = pack;
        }
    }
}

// ---- output projection: 128(M)x64(N), BK=64 swizzled, dbuf, 8 WAVES (r7) ----
__global__ __launch_bounds__(512, 4) void k_gemm_out(
    const bf16* __restrict__ X, const bf16* __restrict__ wob,
    const float* __restrict__ bo, float* __restrict__ out) {
    constexpr int K = DM, BK = 64, NS = K / BK;   // 16 steps
    const int m0 = blockIdx.y * 128, n0 = blockIdx.x * 64;
    __shared__ bf16 sA[2][128 * BK];   // 32 KB
    __shared__ bf16 sB[2][64 * BK];    // 16 KB
    const int tid = threadIdx.x;
    const int l = tid & 63, w = tid >> 6;
    const int quad = l >> 4, l15 = l & 15;
    const int wm = w & 1, wn = w >> 1;
    const int srow = l >> 3;
    const int scol = ((l & 7) ^ srow) * 8;

#pragma unroll
    for (int i = 0; i < 2; ++i) {
        int g8 = (w * 2 + i) * 8;
        llds16(X + (size_t)(m0 + g8 + srow) * K + scol, &sA[0][g8 * BK]);
    }
    llds16(wob + (size_t)(n0 + w * 8 + srow) * K + scol, &sB[0][(w * 8) * BK]);

    f32x4 acc[4] = {};
    for (int s = 0; s < NS; ++s) {
        __syncthreads();
        const int cur = s & 1;
        if (s + 1 < NS) {
            const int k0 = (s + 1) * BK;
#pragma unroll
            for (int i = 0; i < 2; ++i) {
                int g8 = (w * 2 + i) * 8;
                llds16(X + (size_t)(m0 + g8 + srow) * K + k0 + scol, &sA[cur ^ 1][g8 * BK]);
            }
            llds16(wob + (size_t)(n0 + w * 8 + srow) * K + k0 + scol, &sB[cur ^ 1][(w * 8) * BK]);
        }

#pragma unroll
        for (int kk = 0; kk < 2; ++kk) {
            bf16x8 af[4], bfr;
            {
                int row = wn * 16 + l15;
                int byt = (row * 128 + kk * 64 + quad * 16) ^ ((row & 7) << 4);
                bfr = *(const bf16x8*)((const char*)&sB[cur][0] + byt);
            }
#pragma unroll
            for (int mi = 0; mi < 4; ++mi) {
                int row = wm * 64 + mi * 16 + l15;
                int byt = (row * 128 + kk * 64 + quad * 16) ^ ((row & 7) << 4);
                af[mi] = *(const bf16x8*)((const char*)&sA[cur][0] + byt);
            }
#pragma unroll
            for (int mi = 0; mi < 4; ++mi)
                acc[mi] = MFMA32(af[mi], bfr, acc[mi]);
        }
    }
    {
        int col = n0 + wn * 16 + l15;
        float bias_v = bo[col];
#pragma unroll
        for (int mi = 0; mi < 4; ++mi) {
            int rbase = m0 + wm * 64 + mi * 16 + quad * 4;
#pragma unroll
            for (int r = 0; r < 4; ++r)
                out[(size_t)(rbase + r) * DM + col] = acc[mi][r] + bias_v;
        }
    }
}

// ---------------- causal flash attention: P stays in registers (zero-shuffle) ----------------
// r5 structure verbatim (measured best; r6 8-wave and r10 wave-split both
// regressed -> per-iter compute body is the cost, not staging). This round adds
// T5 s_setprio around the MFMA clusters: 4 independent blocks/CU at different j
// = cross-block wave-phase diversity (m191 attn regime, +4-7%), unlike the
// lockstep GEMM case (m190 null). Zero cost if null.
__global__ __launch_bounds__(256, 4) void k_flash(const bf16* __restrict__ Qf,
                                                  const bf16* __restrict__ Kf,
                                                  const bf16* __restrict__ Vf,
                                                  bf16* __restrict__ X) {
    const int bh = blockIdx.x;
    const int qt = 31 - (int)blockIdx.y;      // LPT order
    const int b = bh >> 4, h = bh & 15;
    const int tid = threadIdx.x, w = tid >> 6, l = tid & 63;
    const int quad = l >> 4, l15 = l & 15;
    __shared__ bf16 sKV[2][16 * 512];         // [buf][e]: e 0..7 = K (ni*2+c), 8..15 = V (8+c*4+dt)

    const bf16* qfp = Qf + (size_t)bh * 128 * 1024;
    const bf16* kfp = Kf + (size_t)bh * 128 * 1024;
    const bf16* vfp = Vf + (size_t)bh * 64 * 4 * 512;

    const int qt16 = qt * 4 + w;              // wave's 16-query tile (s16 index)
    const int qglob = qt16 * 16 + l15;

    // persistent Q B-frags (d 0..31, 32..63)
    bf16x8 qf[2];
#pragma unroll
    for (int c = 0; c < 2; ++c)
        qf[c] = *(const bf16x8*)(qfp + ((size_t)qt16 * 2 + c) * 512 + (size_t)l * 8);

    f32x4 o[4] = {};            // O^T: row = d-in-16 (per dtile), col = query = l15
    float lp = 0.f;             // per-lane partial softmax denom

    // preload tile 0: wave w stages entries w*4..w*4+3
#pragma unroll
    for (int i = 0; i < 4; ++i) {
        int e = w * 4 + i;
        const bf16* src = (e < 8) ? kfp + ((size_t)e) * 512
                                  : vfp + ((size_t)(e - 8)) * 512;
        llds16(src + (size_t)l * 8, &sKV[0][e * 512]);
    }

    for (int j = 0; j <= qt; ++j) {
        __syncthreads();        // staging of tile j (issued last iter) now visible
        const bf16* cur = sKV[j & 1];
        if (j < qt) {
            int j1 = j + 1;
#pragma unroll
            for (int i = 0; i < 4; ++i) {
                int e = w * 4 + i;
                const bf16* src = (e < 8) ? kfp + ((size_t)(j1 * 8 + e)) * 512
                                          : vfp + ((size_t)(j1 * 8 + (e - 8))) * 512;
                llds16(src + (size_t)l * 8, (void*)&sKV[j1 & 1][e * 512]);
            }
        }

        // ---- S^T = K·Q^T per 16-key subtile (frags from LDS, stride-1) ----
        f32x4 st[4];
        __builtin_amdgcn_s_setprio(1);
#pragma unroll
        for (int ni = 0; ni < 4; ++ni) {
            bf16x8 k0 = *(const bf16x8*)&cur[(size_t)(ni * 2 + 0) * 512 + l * 8];
            bf16x8 k1 = *(const bf16x8*)&cur[(size_t)(ni * 2 + 1) * 512 + l * 8];
            f32x4 zz = {};
            zz = MFMA32(k0, qf[0], zz);
            st[ni] = MFMA32(k1, qf[1], zz);
        }
        __builtin_amdgcn_s_setprio(0);

        // ---- fixed-m softmax (log2 domain) + in-register P + PV per 32-key chunk ----
        const bool diag = (j == qt);
#pragma unroll
        for (int c = 0; c < 2; ++c) {
            bf16x8 pb;
#pragma unroll
            for (int half = 0; half < 2; ++half) {
                int ni = 2 * c + half;
#pragma unroll
                for (int r = 0; r < 4; ++r) {
                    float s = st[ni][r];
                    if (diag) {
                        int key = j * 64 + ni * 16 + quad * 4 + r;
                        if (key > qglob) s = -1e30f;
                    }
                    float e = __builtin_amdgcn_exp2f(s);
                    lp += e;
                    pb[half * 4 + r] = (bf16)e;
                }
            }
            __builtin_amdgcn_s_setprio(1);
#pragma unroll
            for (int dt = 0; dt < 4; ++dt) {
                bf16x8 vv = *(const bf16x8*)&cur[(size_t)(8 + c * 4 + dt) * 512 + l * 8];
                o[dt] = MFMA32(vv, pb, o[dt]);
            }
            __builtin_amdgcn_s_setprio(0);
        }
    }

    // ---- reduce denom across quads (queries are per-lane) ----
    lp += __shfl_xor(lp, 16, 64);
    lp += __shfl_xor(lp, 32, 64);
    float rv = 1.f / lp;

    // ---- normalize, repack via LDS (reuse sKV after barrier), coalesced store ----
    __syncthreads();            // all waves done reading sKV
    bf16* Xw = &sKV[0][w * 16 * 72];   // wave-private repack region (4 x 2304 B)
#pragma unroll
    for (int dt = 0; dt < 4; ++dt) {
        bf16x4 pk;
#pragma unroll
        for (int r = 0; r < 4; ++r)
            pk[r] = (bf16)(o[dt][r] * rv);
        *(bf16x4*)&Xw[l15 * 72 + dt * 16 + quad * 4] = pk;
    }
#pragma unroll
    for (int i = 0; i < 2; ++i) {
        int row = i * 8 + (l >> 3);
        bf16x8 vv = *(const bf16x8*)&Xw[row * 72 + (l & 7) * 8];
        *(bf16x8*)(X + (size_t)(b * SEQ + qt16 * 16 + row) * DM + h * 64 + (l & 7) * 8) = vv;
    }
}

// ---------------- launcher ----------------
extern "C" void kernel_launch(void* const* d_in, const int* in_sizes, int n_in,
                              void* d_out, int out_size, void* d_ws, size_t ws_size,
                              hipStream_t stream) {
    const float* q  = (const float*)d_in[0];
    const float* k  = (const float*)d_in[1];
    const float* v  = (const float*)d_in[2];
    // d_in[3] = mask: causal tril, handled analytically
    const float* wq = (const float*)d_in[4];
    const float* bq = (const float*)d_in[5];
    const float* wk = (const float*)d_in[6];
    const float* bk = (const float*)d_in[7];
    const float* wv = (const float*)d_in[8];
    const float* bv = (const float*)d_in[9];
    const float* wo = (const float*)d_in[10];
    const float* bo = (const float*)d_in[11];
    float* out = (float*)d_out;

    uint8_t* ws = (uint8_t*)d_ws;
    const size_t SZ_ACT = (size_t)MROWS * DM * sizeof(bf16);  // 8 MB
    const size_t SZ_W   = (size_t)DM * DM * sizeof(bf16);     // 2 MB
    bf16* qb  = (bf16*)(ws);
    bf16* kb  = (bf16*)(ws + SZ_ACT);
    bf16* vb  = (bf16*)(ws + 2 * SZ_ACT);
    bf16* wqb = (bf16*)(ws + 3 * SZ_ACT);
    bf16* wkb = (bf16*)(ws + 3 * SZ_ACT + SZ_W);
    bf16* wvb = (bf16*)(ws + 3 * SZ_ACT + 2 * SZ_W);
    bf16* wob = (bf16*)(ws + 3 * SZ_ACT + 3 * SZ_W);
    bf16* Qf  = (bf16*)(ws + 3 * SZ_ACT + 4 * SZ_W);
    bf16* Kf  = (bf16*)(ws + 4 * SZ_ACT + 4 * SZ_W);
    bf16* Vf  = (bf16*)(ws + 5 * SZ_ACT + 4 * SZ_W);
    bf16* X   = (bf16*)(ws + 6 * SZ_ACT + 4 * SZ_W);
    // total: 7*SZ_ACT + 4*SZ_W = 64 MB

    // 1) convert to bf16
    {
        long total_vec4 = 3L * MROWS * DM / 4 + 4L * DM * DM / 4;
        k_convert<<<dim3((unsigned)(total_vec4 / 256)), 256, 0, stream>>>(
            q, k, v, wq, wk, wv, wo, qb, kb, vb, wqb, wkb, wvb, wob);
    }
    // 2) merged Q/K/V projections: 128x64 tiles, BK=64 swizzled, 8 waves, 32 waves/CU
    k_gemm_qkv<<<dim3(512, 1, 3), 512, 0, stream>>>(
        qb, kb, vb, wqb, wkb, wvb, bq, bk, bv, Qf, Kf, Vf);
    // 3) causal flash attention (r5 structure + T5 setprio, 64-query blocks, LPT)
    k_flash<<<dim3(BATCH * NH, SEQ / 64), 256, 0, stream>>>(Qf, Kf, Vf, X);
    // 4) output projection -> fp32 (128x64 tiles, BK=64 swizzled, 8 waves, dbuf)
    k_gemm_out<<<dim3(DM / 64, MROWS / 128), 512, 0, stream>>>(X, wob, bo, out);
}